// Round 2
// baseline (126.366 us; speedup 1.0000x reference)
//
#include <hip/hip_runtime.h>

// Modulated deformable conv2d, fp32 in/out, bf16 MFMA core.
// B=4, C=64, H=W=128, O=64, K=3x3, stride=1, pad=1, dil=1, og=1, groups=1.
//
// Round 7: latency-bound fix (counters: MfmaUtil 3.4, VALUBusy 21, HBM 12%,
// Occupancy 32.6 -> nothing saturated, waves capped at 4/SIMD by grid).
//  1. K-split wave pairs: each 16-px strip handled by 2 waves (q=0: ch 0-31,
//     q=1: ch 32-63). Waves double to 8192 (100% cap), per-wave chain halves,
//     pair waves share the same NHWC 128B lines (L1 reuse). Pairwise partial
//     sums reduced via 16 KB LDS with ONE end barrier.
//  2. __launch_bounds__(512, 8) to hold VGPR <= 64 (8 waves/SIMD).
//  3. nhwc + wfrag merged into one prep launch (3 -> 2 kernels).
// Fragment layouts (m89/m120-verified): A[m=lane&15][k=quad*8+j],
// B[k=quad*8+j][n=lane&15], D[row=quad*4+reg][col=lane&15].

#define BB 4
#define CC 64
#define HH 128
#define WW 128
#define OO 64
#define KHW 3
#define KK 9
#define HW (HH * WW)

typedef __bf16 bf16_t;
typedef bf16_t bf16x8 __attribute__((ext_vector_type(8)));
typedef float f32x4 __attribute__((ext_vector_type(4)));

// ---- prep: x (NCHW fp32) -> xt (NHWC bf16)  +  weight -> B-fragment bf16 ----
// blocks [0, BB*256): transpose; blocks [BB*256, +144): weight repack.
__global__ __launch_bounds__(256) void prep_kernel(const float* __restrict__ x,
                                                   bf16_t* __restrict__ xt,
                                                   const float* __restrict__ w,
                                                   bf16_t* __restrict__ wf) {
    __shared__ float tile[64 * 65];
    const int t = threadIdx.x;
    if (blockIdx.x < BB * 256) {
        const int b  = blockIdx.x >> 8;
        const int p0 = (blockIdx.x & 255) << 6;
#pragma unroll
        for (int i = 0; i < 16; ++i) {
            int c = i * 4 + (t >> 6);
            int p = t & 63;
            tile[c * 65 + p] = x[(b * CC + c) * HW + p0 + p];  // coalesced
        }
        __syncthreads();
#pragma unroll
        for (int i = 0; i < 16; ++i) {
            int p = i * 4 + (t >> 6);
            int c = t & 63;
            xt[(size_t)((b * HW) + p0 + p) * CC + c] = (bf16_t)tile[c * 65 + p];
        }
    } else {
        // wf element index: ((tap*2+q)*4+nt)*64*8 + lane*8 + j
        //   holds W[o = nt*16 + (lane&15)][c = q*32 + (lane>>4)*8 + j][tap]
        int i = (blockIdx.x - BB * 256) * 256 + t;
        if (i >= OO * CC * KK) return;
        int j    = i & 7;
        int lane = (i >> 3) & 63;
        int nt   = (i >> 9) & 3;
        int q    = (i >> 11) & 1;
        int k    = i >> 12;
        int o = nt * 16 + (lane & 15);
        int c = q * 32 + ((lane >> 4) << 3) + j;
        wf[i] = (bf16_t)w[(o * CC + c) * KK + k];
    }
}

__global__ __launch_bounds__(512, 8) void deform_conv_mfma(
    const bf16_t* __restrict__ xt, const float* __restrict__ offset,
    const float* __restrict__ mask, const bf16x8* __restrict__ wf,
    const float* __restrict__ bias, float* __restrict__ out) {
    const int t     = threadIdx.x;
    const int b     = blockIdx.x >> 8;
    const int p0    = (blockIdx.x & 255) << 6;  // 64-pixel group
    const int lane  = t & 63;
    const int wv    = t >> 6;                   // 0..7
    const int strip = wv >> 1;                  // 0..3: 16-pixel strip
    const int q     = wv & 1;                   // K-half: ch q*32..q*32+31
    const int m0    = strip << 4;
    const int col   = lane & 15;                // A-row m == pixel in strip
    const int quad  = lane >> 4;
    const int rem   = p0 + m0 + col;            // this lane's pixel
    const int ho    = rem >> 7;
    const int wo    = rem & (WW - 1);
    const int cb    = q * 32 + (quad << 3);     // this lane's 8-ch slot

    const bf16_t* xb  = xt + (size_t)b * HW * CC;
    const float* offp = offset + (size_t)b * (2 * KK) * HW + rem;
    const float* mp   = mask + (size_t)b * KK * HW + rem;

    f32x4 acc[4];
#pragma unroll
    for (int nt = 0; nt < 4; ++nt) acc[nt] = (f32x4){0.f, 0.f, 0.f, 0.f};

    // 1-deep pipeline on the offset/mask scalars.
    float offy = offp[0];
    float offx = offp[HW];
    float mm   = mp[0];

    for (int k = 0; k < KK; ++k) {
        float n_offy = 0.f, n_offx = 0.f, n_mm = 0.f;
        if (k < KK - 1) {
            n_offy = offp[(2 * k + 2) * HW];
            n_offx = offp[(2 * k + 3) * HW];
            n_mm   = mp[(k + 1) * HW];
        }

        // ---- per-lane bilinear setup for pixel `rem`, tap k ----
        float py = offy + (float)(k / KHW) + (float)(ho - 1);
        float px = offx + (float)(k % KHW) + (float)(wo - 1);
        float fy0 = floorf(py), fx0 = floorf(px);
        float ly = py - fy0, lx = px - fx0;
        int y0 = (int)fy0, x0 = (int)fx0;
        int y1 = y0 + 1, x1 = x0 + 1;
        bool vy0 = (y0 >= 0) && (y0 < HH);
        bool vy1 = (y1 >= 0) && (y1 < HH);
        bool vx0 = (x0 >= 0) && (x0 < WW);
        bool vx1 = (x1 >= 0) && (x1 < WW);
        int cy0 = min(max(y0, 0), HH - 1), cy1 = min(max(y1, 0), HH - 1);
        int cx0 = min(max(x0, 0), WW - 1), cx1 = min(max(x1, 0), WW - 1);
        float w0 = (vy0 && vx0) ? mm * (1.0f - ly) * (1.0f - lx) : 0.0f;
        float w1 = (vy0 && vx1) ? mm * (1.0f - ly) * lx : 0.0f;
        float w2 = (vy1 && vx0) ? mm * ly * (1.0f - lx) : 0.0f;
        float w3 = (vy1 && vx1) ? mm * ly * lx : 0.0f;

        // ---- gather this lane's own 8-channel A-fragment slot ----
        bf16x8 a00 = *(const bf16x8*)(xb + (size_t)(cy0 * WW + cx0) * CC + cb);
        bf16x8 a01 = *(const bf16x8*)(xb + (size_t)(cy0 * WW + cx1) * CC + cb);
        bf16x8 a10 = *(const bf16x8*)(xb + (size_t)(cy1 * WW + cx0) * CC + cb);
        bf16x8 a11 = *(const bf16x8*)(xb + (size_t)(cy1 * WW + cx1) * CC + cb);

        bf16x8 af;
#pragma unroll
        for (int i = 0; i < 8; ++i) {
            float v = w0 * (float)a00[i] + w1 * (float)a01[i] +
                      w2 * (float)a10[i] + w3 * (float)a11[i];
            af[i] = (bf16_t)v;
        }

        // ---- MFMA: 16 pixels x 64 outputs, this wave's K=32 half ----
#pragma unroll
        for (int nt = 0; nt < 4; ++nt) {
            bf16x8 bfg = wf[((k * 2 + q) * 4 + nt) * 64 + lane];
            acc[nt] = __builtin_amdgcn_mfma_f32_16x16x32_bf16(
                af, bfg, acc[nt], 0, 0, 0);
        }

        offy = n_offy;
        offx = n_offx;
        mm   = n_mm;
    }

    // ---- pairwise K-half reduction through LDS, then epilogue ----
    __shared__ f32x4 red[4][64][4];   // 16 KB
    if (q) {
#pragma unroll
        for (int nt = 0; nt < 4; ++nt) red[strip][lane][nt] = acc[nt];
    }
    __syncthreads();
    if (!q) {
#pragma unroll
        for (int nt = 0; nt < 4; ++nt) {
            int o = nt * 16 + col;
            float bv = bias[o];
            f32x4 r = acc[nt] + red[strip][lane][nt];
            r.x += bv; r.y += bv; r.z += bv; r.w += bv;
            // D[row=quad*4+reg][col]; row -> pixel, col -> output
            float* dst = out + (size_t)(b * OO + o) * HW + p0 + m0 + quad * 4;
            *(f32x4*)dst = r;  // 4 consecutive pixels, 16B aligned
        }
    }
}

extern "C" void kernel_launch(void* const* d_in, const int* in_sizes, int n_in,
                              void* d_out, int out_size, void* d_ws,
                              size_t ws_size, hipStream_t stream) {
    const float* x      = (const float*)d_in[0];
    const float* offset = (const float*)d_in[1];
    const float* mask   = (const float*)d_in[2];
    const float* weight = (const float*)d_in[3];
    const float* bias   = (const float*)d_in[4];
    float* out = (float*)d_out;

    bf16_t* xt  = (bf16_t*)d_ws;                       // 4*16384*64*2 = 8 MB
    bf16_t* wfr = (bf16_t*)((char*)d_ws + (size_t)BB * HW * CC * 2);  // 72 KB

    int nwf_blocks = (OO * CC * KK + 255) / 256;       // 144
    prep_kernel<<<BB * 256 + nwf_blocks, 256, 0, stream>>>(x, xt, weight, wfr);

    deform_conv_mfma<<<BB * (HW / 64), 512, 0, stream>>>(
        xt, offset, mask, (const bf16x8*)wfr, bias, out);
}